// Round 5
// baseline (331.666 us; speedup 1.0000x reference)
//
#include <hip/hip_runtime.h>

#define N_NODES 50000
#define N_EDGES 800000
#define IN_DIM 100
#define OUT_DIM 40
#define ROW 50            // 50 dwords = 100 bf16 per node row (used)
#define ROW_PAD 64        // padded pitch: 256 B -> every row = 2 aligned 128B lines
#define SCAN_B 512
#define NSCAN_BLK ((N_NODES + SCAN_B - 1) / SCAN_B)   // 98

typedef unsigned int uint;

// ---- bf16 helpers (packed pair in one dword) ----
__device__ __forceinline__ float bflo(uint u) { return __uint_as_float(u << 16); }
__device__ __forceinline__ float bfhi(uint u) { return __uint_as_float(u & 0xffff0000u); }
__device__ __forceinline__ uint packbf(float a, float b) {
    uint ua = __float_as_uint(a), ub = __float_as_uint(b);
    ua = (ua + 0x7fffu + ((ua >> 16) & 1u)) >> 16;      // RNE
    ub = (ub + 0x7fffu + ((ub >> 16) & 1u)) >> 16;
    return ua | (ub << 16);
}

// ---------------- zero scratch: {deg, colsum, colsq} + 3 pad rows ----------------
__global__ void zero_kernel(int* p, int n, uint* fs, uint* bufA, uint* bufB) {
    int i = blockIdx.x * blockDim.x + threadIdx.x;
    if (i < n) p[i] = 0;
    if (i < ROW) {
        fs[(size_t)N_NODES * ROW_PAD + i] = 0u;
        bufA[(size_t)N_NODES * ROW_PAD + i] = 0u;
        bufB[(size_t)N_NODES * ROW_PAD + i] = 0u;
    }
}

// ---------------- in-degree; keep returned old count as the edge's slot ----------------
__global__ void deg_kernel(const int* __restrict__ dst, int* __restrict__ deg,
                           int* __restrict__ eoff) {
    int e = blockIdx.x * blockDim.x + threadIdx.x;
    if (e < N_EDGES) eoff[e] = atomicAdd(&deg[dst[e]], 1);
}

// ---------------- scan phase 1 ----------------
__global__ __launch_bounds__(SCAN_B) void scan1_kernel(const int* __restrict__ deg,
                                                       int* __restrict__ rowptr,
                                                       float* __restrict__ norm,
                                                       float* __restrict__ norm2,
                                                       int* __restrict__ blocksum) {
    int i = blockIdx.x * SCAN_B + threadIdx.x;
    int lane = threadIdx.x & 63, wid = threadIdx.x >> 6;
    int d = (i < N_NODES) ? deg[i] : 0;
    int v = d;
#pragma unroll
    for (int off = 1; off < 64; off <<= 1) {
        int t = __shfl_up(v, off);
        if (lane >= off) v += t;
    }
    __shared__ int wsum[8];
    if (lane == 63) wsum[wid] = v;
    __syncthreads();
    if (threadIdx.x < 8) {
        int w = wsum[threadIdx.x];
#pragma unroll
        for (int off = 1; off < 8; off <<= 1) {
            int t = __shfl_up(w, off);
            if (lane >= off) w += t;
        }
        wsum[threadIdx.x] = w;
    }
    __syncthreads();
    int woff = wid ? wsum[wid - 1] : 0;
    int incl = woff + v;
    if (i < N_NODES) {
        rowptr[i] = incl - d;
        float n1 = 1.0f / sqrtf((float)max(d, 1));
        norm[i] = n1;
        norm2[i] = n1 * n1;
    }
    if (threadIdx.x == SCAN_B - 1) blocksum[blockIdx.x] = incl;
}

// ---------------- scan phase 2 ----------------
__global__ __launch_bounds__(128) void scan2_kernel(const int* __restrict__ blocksum,
                                                    int* __restrict__ blockoff,
                                                    int* __restrict__ rowptr) {
    __shared__ int s[128];
    int t = threadIdx.x;
    int v = (t < NSCAN_BLK) ? blocksum[t] : 0;
    s[t] = v;
    __syncthreads();
    for (int off = 1; off < 128; off <<= 1) {
        int u = (t >= off) ? s[t - off] : 0;
        __syncthreads();
        s[t] += u;
        __syncthreads();
    }
    if (t < NSCAN_BLK) blockoff[t] = s[t] - v;
    if (t == 127) rowptr[N_NODES] = s[127];
}

// ---------------- scan phase 3 ----------------
__global__ __launch_bounds__(SCAN_B) void scan3_kernel(int* __restrict__ rowptr,
                                                       const int* __restrict__ blockoff) {
    int i = blockIdx.x * SCAN_B + threadIdx.x;
    if (i < N_NODES) rowptr[i] += blockoff[blockIdx.x];
}

// ---------------- CSR scatter, atomic-free (slot precomputed in eoff) ----------------
__global__ void csr_fill_kernel(const int* __restrict__ src, const int* __restrict__ dst,
                                const int* __restrict__ rowptr,
                                const int* __restrict__ eoff,
                                int* __restrict__ csr) {
    int e = blockIdx.x * blockDim.x + threadIdx.x;
    if (e < N_EDGES) csr[rowptr[dst[e]] + eoff[e]] = src[e];
}

// ---------------- pre-scale: fs = bf16(norm ⊙ feat), padded pitch ----------------
__global__ __launch_bounds__(256) void prescale_kernel(const float* __restrict__ feat,
                                                       const float* __restrict__ norm,
                                                       uint* __restrict__ fs) {
    int i = blockIdx.x * 256 + threadIdx.x;
    if (i < N_NODES * ROW) {
        int n = i / ROW;
        int p = i - n * ROW;
        const float2 v = ((const float2*)feat)[i];
        float nm = norm[n];
        fs[(size_t)n * ROW_PAD + p] = packbf(v.x * nm, v.y * nm);
    }
}

// ---------------- SGC hop: out[n] = bf16( scale[n] * sum_{s in N(n)} H[s] ) ----
// 2 nodes per 128-thread block (one wave each). 8-deep gather unroll (mean
// degree 16 -> ~17% pad waste); dummy edges -> zero pad row N_NODES. Rows
// padded to 256B so each gather is exactly two aligned 128B lines.
__global__ __launch_bounds__(128) void spmm_kernel(const uint* __restrict__ H,
                                                   const int* __restrict__ rowptr,
                                                   const int* __restrict__ csr,
                                                   const float* __restrict__ scale,
                                                   uint* __restrict__ out) {
    const int n = blockIdx.x * 2 + (threadIdx.x >> 6);
    const int l = threadIdx.x & 63;
    const int ll = min(l, ROW - 1);
    const int beg = rowptr[n], end = rowptr[n + 1];
    float ax = 0.f, ay = 0.f;
    for (int j = beg; j < end; j += 8) {
        int s[8];
#pragma unroll
        for (int k = 0; k < 8; ++k)
            s[k] = (j + k < end) ? csr[j + k] : N_NODES;   // csr padded, safe
        uint u[8];
#pragma unroll
        for (int k = 0; k < 8; ++k)
            u[k] = H[((size_t)s[k] << 6) + ll];            // <<6 == *ROW_PAD
#pragma unroll
        for (int k = 0; k < 8; ++k) { ax += bflo(u[k]); ay += bfhi(u[k]); }
    }
    if (l < ROW) {
        float sc = scale[n];
        out[((size_t)n << 6) + l] = packbf(ax * sc, ay * sc);
    }
}

// ---------------- per-feature sum/sumsq over bf16 h3 (padded pitch) ----------------
#define CS_BLOCKS 625
#define CS_THREADS 256   // 160000 threads, 160000 % 50 == 0 -> fixed pair per thread
__global__ __launch_bounds__(CS_THREADS) void col_stats_kernel(const uint* __restrict__ h,
                                                               float* __restrict__ colsum,
                                                               float* __restrict__ colsq) {
    int gtid = blockIdx.x * CS_THREADS + threadIdx.x;
    const int stride = CS_BLOCKS * CS_THREADS;
    float s0 = 0.f, s1 = 0.f, q0 = 0.f, q1 = 0.f;
    for (int i = gtid; i < N_NODES * ROW; i += stride) {
        int n = i / ROW;
        int p = i - n * ROW;
        uint u = h[((size_t)n << 6) + p];
        float a = bflo(u), b = bfhi(u);
        s0 += a; s1 += b; q0 += a * a; q1 += b * b;
    }
    __shared__ float ssum[IN_DIM], ssq[IN_DIM];
    if (threadIdx.x < IN_DIM) { ssum[threadIdx.x] = 0.f; ssq[threadIdx.x] = 0.f; }
    __syncthreads();
    int p = gtid % ROW;
    atomicAdd(&ssum[2 * p], s0);
    atomicAdd(&ssum[2 * p + 1], s1);
    atomicAdd(&ssq[2 * p], q0);
    atomicAdd(&ssq[2 * p + 1], q1);
    __syncthreads();
    if (threadIdx.x < IN_DIM) {
        atomicAdd(&colsum[threadIdx.x], ssum[threadIdx.x]);
        atomicAdd(&colsq[threadIdx.x], ssq[threadIdx.x]);
    }
}

// ---------------- fold standardize into W,b ----------------
__global__ __launch_bounds__(256) void prep_kernel(const float* __restrict__ colsum,
                                                   const float* __restrict__ colsq,
                                                   const float* __restrict__ W,
                                                   const float* __restrict__ b,
                                                   float* __restrict__ Wt,
                                                   float* __restrict__ bp) {
    __shared__ float smean[IN_DIM];
    __shared__ float sinv[IN_DIM];
    int t = threadIdx.x;
    const float Nf = (float)N_NODES;
    if (t < IN_DIM) {
        float m = colsum[t] / Nf;
        float var = (colsq[t] - Nf * m * m) / (Nf - 1.0f);
        var = fmaxf(var, 1e-20f);
        smean[t] = m;
        sinv[t] = 1.0f / sqrtf(var);
    }
    __syncthreads();
    for (int i = t; i < IN_DIM * OUT_DIM; i += 256) {
        int o = i % OUT_DIM, f = i / OUT_DIM;
        Wt[f * OUT_DIM + o] = W[o * IN_DIM + f] * sinv[f];
    }
    if (t < OUT_DIM) {
        float acc = b[t];
        for (int f = 0; f < IN_DIM; ++f)
            acc -= smean[f] * W[t * IN_DIM + f] * sinv[f];
        bp[t] = acc;
    }
}

// ---------------- final linear over bf16 h3 (padded pitch), W' in LDS ----------------
__global__ __launch_bounds__(256) void final_kernel(const uint* __restrict__ h,
                                                    const float* __restrict__ Wt,
                                                    const float* __restrict__ bp,
                                                    float* __restrict__ out) {
    __shared__ float sW[IN_DIM * OUT_DIM];   // 16 KB
    __shared__ float sb[OUT_DIM];
    for (int i = threadIdx.x; i < IN_DIM * OUT_DIM; i += 256) sW[i] = Wt[i];
    if (threadIdx.x < OUT_DIM) sb[threadIdx.x] = bp[threadIdx.x];
    __syncthreads();
    int t = blockIdx.x * 256 + threadIdx.x;
    if (t >= N_NODES * OUT_DIM) return;
    int n = t / OUT_DIM;
    int o = t - n * OUT_DIM;
    const uint* hr = h + ((size_t)n << 6);
    float acc = sb[o];
#pragma unroll 10
    for (int p = 0; p < ROW; ++p) {
        uint u = hr[p];
        acc += bflo(u) * sW[(2 * p) * OUT_DIM + o];
        acc += bfhi(u) * sW[(2 * p + 1) * OUT_DIM + o];
    }
    out[t] = acc;
}

extern "C" void kernel_launch(void* const* d_in, const int* in_sizes, int n_in,
                              void* d_out, int out_size, void* d_ws, size_t ws_size,
                              hipStream_t stream) {
    const float* feat = (const float*)d_in[0];   // [50000,100]
    const float* W    = (const float*)d_in[1];   // [40,100]
    const float* b    = (const float*)d_in[2];   // [40]
    const int*   src  = (const int*)d_in[3];     // [800000]
    const int*   dst  = (const int*)d_in[4];     // [800000]
    float* out = (float*)d_out;                  // [50000,40]

    char* w = (char*)d_ws;
    int*   deg      = (int*)w;    w += N_NODES * 4;
    float* colsum   = (float*)w;  w += 128 * 4;
    float* colsq    = (float*)w;  w += 128 * 4;
    // ---- end of zero region: (N_NODES + 256) ints ----
    int*   eoff     = (int*)w;    w += N_EDGES * 4;
    int*   rowptr   = (int*)w;    w += 50004 * 4;
    float* norm     = (float*)w;  w += N_NODES * 4;
    float* norm2    = (float*)w;  w += N_NODES * 4;
    int*   blocksum = (int*)w;    w += 128 * 4;
    int*   blockoff = (int*)w;    w += 128 * 4;
    int*   csr      = (int*)w;    w += (N_EDGES + 64) * 4;   // +64 pad for unroll reads
    float* Wt       = (float*)w;  w += IN_DIM * OUT_DIM * 4;
    float* bp       = (float*)w;  w += 64 * 4;
    // align row buffers to 256 B
    w = (char*)(((size_t)w + 255) & ~(size_t)255);
    const size_t HB = (size_t)(N_NODES + 1) * ROW_PAD * 4;   // padded rows + zero pad row
    uint*  fs       = (uint*)w;   w += HB;
    uint*  bufA     = (uint*)w;   w += HB;
    uint*  bufB     = (uint*)w;   w += HB;

    // 1. zero {deg, colsum, colsq} + pad rows (one dispatch)
    {
        int nz = N_NODES + 256;
        zero_kernel<<<(nz + 255) / 256, 256, 0, stream>>>(deg, nz, fs, bufA, bufB);
    }
    // 2. in-degree + per-edge slot (single atomic per edge total)
    deg_kernel<<<(N_EDGES + 255) / 256, 256, 0, stream>>>(dst, deg, eoff);
    // 3. rowptr (3-phase scan) + norm/norm2
    scan1_kernel<<<NSCAN_BLK, SCAN_B, 0, stream>>>(deg, rowptr, norm, norm2, blocksum);
    scan2_kernel<<<1, 128, 0, stream>>>(blocksum, blockoff, rowptr);
    scan3_kernel<<<NSCAN_BLK, SCAN_B, 0, stream>>>(rowptr, blockoff);
    // 4. CSR scatter (no atomics)
    csr_fill_kernel<<<(N_EDGES + 255) / 256, 256, 0, stream>>>(src, dst, rowptr, eoff, csr);
    // 5. pre-scale feat by norm into bf16 (padded pitch)
    prescale_kernel<<<(N_NODES * ROW + 255) / 256, 256, 0, stream>>>(feat, norm, fs);
    // 6. three hops: g1 = norm2*S(fs); g2 = norm2*S(g1); h3 = norm*S(g2)
    spmm_kernel<<<N_NODES / 2, 128, 0, stream>>>(fs, rowptr, csr, norm2, bufA);
    spmm_kernel<<<N_NODES / 2, 128, 0, stream>>>(bufA, rowptr, csr, norm2, bufB);
    spmm_kernel<<<N_NODES / 2, 128, 0, stream>>>(bufB, rowptr, csr, norm, bufA);
    // 7. column stats on bf16 h3
    col_stats_kernel<<<CS_BLOCKS, CS_THREADS, 0, stream>>>(bufA, colsum, colsq);
    // 8. fold mean/std into W', b'
    prep_kernel<<<1, 256, 0, stream>>>(colsum, colsq, W, b, Wt, bp);
    // 9. final linear
    {
        int total = N_NODES * OUT_DIM;
        final_kernel<<<(total + 255) / 256, 256, 0, stream>>>(bufA, Wt, bp, out);
    }
}

// Round 6
// 266.611 us; speedup vs baseline: 1.2440x; 1.2440x over previous
//
#include <hip/hip_runtime.h>

#define N_NODES 50000
#define N_EDGES 800000
#define IN_DIM 100
#define OUT_DIM 40
#define ROW 50            // 50 dwords = 100 bf16 per node row (used)
#define ROW_PAD 64        // padded pitch: 256 B -> one row = 16 lanes x dwordx4
#define SCAN_B 512
#define NSCAN_BLK ((N_NODES + SCAN_B - 1) / SCAN_B)   // 98
#define CSR_CAP (N_EDGES + N_NODES * 8 + 64)          // aligned-degree worst case

typedef unsigned int uint;

// ---- bf16 helpers (packed pair in one dword) ----
__device__ __forceinline__ float bflo(uint u) { return __uint_as_float(u << 16); }
__device__ __forceinline__ float bfhi(uint u) { return __uint_as_float(u & 0xffff0000u); }
__device__ __forceinline__ uint packbf(float a, float b) {
    uint ua = __float_as_uint(a), ub = __float_as_uint(b);
    ua = (ua + 0x7fffu + ((ua >> 16) & 1u)) >> 16;      // RNE
    ub = (ub + 0x7fffu + ((ub >> 16) & 1u)) >> 16;
    return ua | (ub << 16);
}

// ---------------- zero scratch: {deg, colsum, colsq} + 3 zero pad-rows ----------------
__global__ void zero_kernel(int* p, int n, uint* fs, uint* bufA, uint* bufB) {
    int i = blockIdx.x * blockDim.x + threadIdx.x;
    if (i < n) p[i] = 0;
    if (i < ROW_PAD) {   // full 256B pad row (index N_NODES)
        fs[(size_t)N_NODES * ROW_PAD + i] = 0u;
        bufA[(size_t)N_NODES * ROW_PAD + i] = 0u;
        bufB[(size_t)N_NODES * ROW_PAD + i] = 0u;
    }
}

// ---------------- in-degree; keep returned old count as the edge's slot ----------------
__global__ void deg_kernel(const int* __restrict__ dst, int* __restrict__ deg,
                           int* __restrict__ eoff) {
    int e = blockIdx.x * blockDim.x + threadIdx.x;
    if (e < N_EDGES) eoff[e] = atomicAdd(&deg[dst[e]], 1);
}

// ---------------- scan phase 1: scan ALIGNED degrees ((d+7)&~7), emit norms ----
__global__ __launch_bounds__(SCAN_B) void scan1_kernel(const int* __restrict__ deg,
                                                       int* __restrict__ rowptr,
                                                       float* __restrict__ norm,
                                                       float* __restrict__ norm2,
                                                       int* __restrict__ blocksum) {
    int i = blockIdx.x * SCAN_B + threadIdx.x;
    int lane = threadIdx.x & 63, wid = threadIdx.x >> 6;
    int d = (i < N_NODES) ? deg[i] : 0;
    int da = (d + 7) & ~7;          // pad each node's edge list to multiple of 8
    int v = da;
#pragma unroll
    for (int off = 1; off < 64; off <<= 1) {
        int t = __shfl_up(v, off);
        if (lane >= off) v += t;
    }
    __shared__ int wsum[8];
    if (lane == 63) wsum[wid] = v;
    __syncthreads();
    if (threadIdx.x < 8) {
        int w = wsum[threadIdx.x];
#pragma unroll
        for (int off = 1; off < 8; off <<= 1) {
            int t = __shfl_up(w, off);
            if (lane >= off) w += t;
        }
        wsum[threadIdx.x] = w;
    }
    __syncthreads();
    int woff = wid ? wsum[wid - 1] : 0;
    int incl = woff + v;
    if (i < N_NODES) {
        rowptr[i] = incl - da;
        float n1 = 1.0f / sqrtf((float)max(d, 1));
        norm[i] = n1;
        norm2[i] = n1 * n1;
    }
    if (threadIdx.x == SCAN_B - 1) blocksum[blockIdx.x] = incl;
}

// ---------------- scan phase 2 ----------------
__global__ __launch_bounds__(128) void scan2_kernel(const int* __restrict__ blocksum,
                                                    int* __restrict__ blockoff,
                                                    int* __restrict__ rowptr) {
    __shared__ int s[128];
    int t = threadIdx.x;
    int v = (t < NSCAN_BLK) ? blocksum[t] : 0;
    s[t] = v;
    __syncthreads();
    for (int off = 1; off < 128; off <<= 1) {
        int u = (t >= off) ? s[t - off] : 0;
        __syncthreads();
        s[t] += u;
        __syncthreads();
    }
    if (t < NSCAN_BLK) blockoff[t] = s[t] - v;
    if (t == 127) rowptr[N_NODES] = s[127];
}

// ---------------- scan phase 3: finalize rowptr + fill CSR pad slots ----------------
__global__ __launch_bounds__(SCAN_B) void scan3_kernel(int* __restrict__ rowptr,
                                                       const int* __restrict__ blockoff,
                                                       const int* __restrict__ deg,
                                                       int* __restrict__ csr) {
    int i = blockIdx.x * SCAN_B + threadIdx.x;
    if (i < N_NODES) {
        int rp = rowptr[i] + blockoff[blockIdx.x];
        rowptr[i] = rp;
        int d = deg[i], da = (d + 7) & ~7;
        for (int k = d; k < da; ++k) csr[rp + k] = N_NODES;   // dummy -> zero row
    }
}

// ---------------- CSR scatter, atomic-free (slot precomputed in eoff) ----------------
__global__ void csr_fill_kernel(const int* __restrict__ src, const int* __restrict__ dst,
                                const int* __restrict__ rowptr,
                                const int* __restrict__ eoff,
                                int* __restrict__ csr) {
    int e = blockIdx.x * blockDim.x + threadIdx.x;
    if (e < N_EDGES) csr[rowptr[dst[e]] + eoff[e]] = src[e];
}

// ---------------- pre-scale: fs = bf16(norm ⊙ feat), full padded rows, uint4 ----
__global__ __launch_bounds__(256) void prescale_kernel(const float* __restrict__ feat,
                                                       const float* __restrict__ norm,
                                                       uint4* __restrict__ fs4) {
    int t = blockIdx.x * 256 + threadIdx.x;   // N_NODES*16 threads
    if (t >= N_NODES * 16) return;
    int n = t >> 4, ql = t & 15;
    float nm = norm[n];
    uint4 o = make_uint4(0u, 0u, 0u, 0u);
    const float4* fr = (const float4*)(feat + (size_t)n * IN_DIM);
    if (ql < 12) {
        float4 a = fr[2 * ql], b2 = fr[2 * ql + 1];
        o.x = packbf(a.x * nm, a.y * nm);  o.y = packbf(a.z * nm, a.w * nm);
        o.z = packbf(b2.x * nm, b2.y * nm); o.w = packbf(b2.z * nm, b2.w * nm);
    } else if (ql == 12) {
        float4 a = fr[24];                 // features 96..99
        o.x = packbf(a.x * nm, a.y * nm);  o.y = packbf(a.z * nm, a.w * nm);
    }
    fs4[t] = o;
}

// ---------------- SGC hop: out[n] = bf16( scale[n] * sum_{s in N(n)} H[s] ) ----
// One wave per node (2 nodes / 128-thr block). Quarter-wave gather: each
// 16-lane quarter loads one full 256B row as dwordx4 -> 4 edges PER
// INSTRUCTION; 2 loads in flight -> 8 edges/iter. Edge lists are 8-aligned
// with dummy slots pointing at the zero row, so no bounds logic in the loop.
__global__ __launch_bounds__(128) void spmm_kernel(const uint4* __restrict__ H4,
                                                   const int* __restrict__ rowptr,
                                                   const int* __restrict__ csr,
                                                   const float* __restrict__ scale,
                                                   uint4* __restrict__ out4) {
    const int n = blockIdx.x * 2 + (threadIdx.x >> 6);
    const int l = threadIdx.x & 63;
    const int q = l >> 4;          // quarter 0..3
    const int ql = l & 15;         // lane within quarter
    const int beg = rowptr[n], end = rowptr[n + 1];   // multiple-of-8 span
    float ax0 = 0.f, ax1 = 0.f, ax2 = 0.f, ax3 = 0.f;
    float ay0 = 0.f, ay1 = 0.f, ay2 = 0.f, ay3 = 0.f;
    for (int j = beg; j < end; j += 8) {
        int s0 = csr[j + q];
        int s1 = csr[j + 4 + q];
        uint4 u0 = H4[(size_t)s0 * 16 + ql];
        uint4 u1 = H4[(size_t)s1 * 16 + ql];
        ax0 += bflo(u0.x); ay0 += bfhi(u0.x);
        ax1 += bflo(u0.y); ay1 += bfhi(u0.y);
        ax2 += bflo(u0.z); ay2 += bfhi(u0.z);
        ax3 += bflo(u0.w); ay3 += bfhi(u0.w);
        ax0 += bflo(u1.x); ay0 += bfhi(u1.x);
        ax1 += bflo(u1.y); ay1 += bfhi(u1.y);
        ax2 += bflo(u1.z); ay2 += bfhi(u1.z);
        ax3 += bflo(u1.w); ay3 += bfhi(u1.w);
    }
    // reduce the 4 quarters (lanes l ^ 16 ^ 32)
    ax0 += __shfl_xor(ax0, 16); ax1 += __shfl_xor(ax1, 16);
    ax2 += __shfl_xor(ax2, 16); ax3 += __shfl_xor(ax3, 16);
    ay0 += __shfl_xor(ay0, 16); ay1 += __shfl_xor(ay1, 16);
    ay2 += __shfl_xor(ay2, 16); ay3 += __shfl_xor(ay3, 16);
    ax0 += __shfl_xor(ax0, 32); ax1 += __shfl_xor(ax1, 32);
    ax2 += __shfl_xor(ax2, 32); ax3 += __shfl_xor(ax3, 32);
    ay0 += __shfl_xor(ay0, 32); ay1 += __shfl_xor(ay1, 32);
    ay2 += __shfl_xor(ay2, 32); ay3 += __shfl_xor(ay3, 32);
    if (q == 0) {
        float sc = scale[n];
        uint4 o;
        o.x = packbf(ax0 * sc, ay0 * sc);
        o.y = packbf(ax1 * sc, ay1 * sc);
        o.z = packbf(ax2 * sc, ay2 * sc);
        o.w = packbf(ax3 * sc, ay3 * sc);
        out4[(size_t)n * 16 + ql] = o;   // full row incl. zero pads
    }
}

// ---------------- per-feature sum/sumsq over padded bf16 h3 ----------------
#define CS_BLOCKS 625
#define CS_THREADS 256   // stride 160000 (mult of 64) -> fixed dword-slot per thread
__global__ __launch_bounds__(CS_THREADS) void col_stats_kernel(const uint* __restrict__ h,
                                                               float* __restrict__ colsum,
                                                               float* __restrict__ colsq) {
    int gtid = blockIdx.x * CS_THREADS + threadIdx.x;
    const int stride = CS_BLOCKS * CS_THREADS;
    const int total = N_NODES * ROW_PAD;
    float s0 = 0.f, s1 = 0.f, q0 = 0.f, q1 = 0.f;
    for (int i = gtid; i < total; i += stride) {   // pads are zero, harmless
        uint u = h[i];
        float a = bflo(u), b = bfhi(u);
        s0 += a; s1 += b; q0 += a * a; q1 += b * b;
    }
    __shared__ float ssum[IN_DIM], ssq[IN_DIM];
    if (threadIdx.x < IN_DIM) { ssum[threadIdx.x] = 0.f; ssq[threadIdx.x] = 0.f; }
    __syncthreads();
    int p = gtid & 63;
    if (p < ROW) {
        atomicAdd(&ssum[2 * p], s0);
        atomicAdd(&ssum[2 * p + 1], s1);
        atomicAdd(&ssq[2 * p], q0);
        atomicAdd(&ssq[2 * p + 1], q1);
    }
    __syncthreads();
    if (threadIdx.x < IN_DIM) {
        atomicAdd(&colsum[threadIdx.x], ssum[threadIdx.x]);
        atomicAdd(&colsq[threadIdx.x], ssq[threadIdx.x]);
    }
}

// ---------------- fold standardize into W,b ----------------
__global__ __launch_bounds__(256) void prep_kernel(const float* __restrict__ colsum,
                                                   const float* __restrict__ colsq,
                                                   const float* __restrict__ W,
                                                   const float* __restrict__ b,
                                                   float* __restrict__ Wt,
                                                   float* __restrict__ bp) {
    __shared__ float smean[IN_DIM];
    __shared__ float sinv[IN_DIM];
    int t = threadIdx.x;
    const float Nf = (float)N_NODES;
    if (t < IN_DIM) {
        float m = colsum[t] / Nf;
        float var = (colsq[t] - Nf * m * m) / (Nf - 1.0f);
        var = fmaxf(var, 1e-20f);
        smean[t] = m;
        sinv[t] = 1.0f / sqrtf(var);
    }
    __syncthreads();
    for (int i = t; i < IN_DIM * OUT_DIM; i += 256) {
        int o = i % OUT_DIM, f = i / OUT_DIM;
        Wt[f * OUT_DIM + o] = W[o * IN_DIM + f] * sinv[f];
    }
    if (t < OUT_DIM) {
        float acc = b[t];
        for (int f = 0; f < IN_DIM; ++f)
            acc -= smean[f] * W[t * IN_DIM + f] * sinv[f];
        bp[t] = acc;
    }
}

// ---------------- final linear: 10 threads/node, uint4 row reads, W' in LDS ----
// sW padded to 104 features (rows 100..103 = 0) so the 13th uint4 (dwords
// 48..51, features 96..103) needs no special-casing.
__global__ __launch_bounds__(256) void final_kernel(const uint4* __restrict__ h4,
                                                    const float* __restrict__ Wt,
                                                    const float* __restrict__ bp,
                                                    float* __restrict__ out) {
    __shared__ float sW[104 * OUT_DIM];   // 16.25 KB
    __shared__ float sb[OUT_DIM];
    for (int i = threadIdx.x; i < 104 * OUT_DIM; i += 256)
        sW[i] = (i < IN_DIM * OUT_DIM) ? Wt[i] : 0.f;
    if (threadIdx.x < OUT_DIM) sb[threadIdx.x] = bp[threadIdx.x];
    __syncthreads();
    int t = blockIdx.x * 256 + threadIdx.x;
    if (t >= N_NODES * 10) return;
    int n = t / 10;
    int og = (t - n * 10) * 4;            // output group of 4
    const uint4* hr = h4 + (size_t)n * 16;
    float a0 = sb[og], a1 = sb[og + 1], a2 = sb[og + 2], a3 = sb[og + 3];
#pragma unroll
    for (int r = 0; r < 13; ++r) {        // dwords 0..51 (50,51 are zero pads)
        uint4 u = hr[r];
        int f = r * 8;
        float v0 = bflo(u.x), v1 = bfhi(u.x), v2 = bflo(u.y), v3 = bfhi(u.y);
        float v4 = bflo(u.z), v5 = bfhi(u.z), v6 = bflo(u.w), v7 = bfhi(u.w);
        const float* w0 = &sW[(f + 0) * OUT_DIM + og];
        const float* w1 = &sW[(f + 1) * OUT_DIM + og];
        const float* w2 = &sW[(f + 2) * OUT_DIM + og];
        const float* w3 = &sW[(f + 3) * OUT_DIM + og];
        const float* w4 = &sW[(f + 4) * OUT_DIM + og];
        const float* w5 = &sW[(f + 5) * OUT_DIM + og];
        const float* w6 = &sW[(f + 6) * OUT_DIM + og];
        const float* w7 = &sW[(f + 7) * OUT_DIM + og];
        a0 += v0 * w0[0] + v1 * w1[0] + v2 * w2[0] + v3 * w3[0]
            + v4 * w4[0] + v5 * w5[0] + v6 * w6[0] + v7 * w7[0];
        a1 += v0 * w0[1] + v1 * w1[1] + v2 * w2[1] + v3 * w3[1]
            + v4 * w4[1] + v5 * w5[1] + v6 * w6[1] + v7 * w7[1];
        a2 += v0 * w0[2] + v1 * w1[2] + v2 * w2[2] + v3 * w3[2]
            + v4 * w4[2] + v5 * w5[2] + v6 * w6[2] + v7 * w7[2];
        a3 += v0 * w0[3] + v1 * w1[3] + v2 * w2[3] + v3 * w3[3]
            + v4 * w4[3] + v5 * w5[3] + v6 * w6[3] + v7 * w7[3];
    }
    float4 o = make_float4(a0, a1, a2, a3);
    *((float4*)(out + (size_t)n * OUT_DIM + og)) = o;
}

extern "C" void kernel_launch(void* const* d_in, const int* in_sizes, int n_in,
                              void* d_out, int out_size, void* d_ws, size_t ws_size,
                              hipStream_t stream) {
    const float* feat = (const float*)d_in[0];   // [50000,100]
    const float* W    = (const float*)d_in[1];   // [40,100]
    const float* b    = (const float*)d_in[2];   // [40]
    const int*   src  = (const int*)d_in[3];     // [800000]
    const int*   dst  = (const int*)d_in[4];     // [800000]
    float* out = (float*)d_out;                  // [50000,40]

    char* w = (char*)d_ws;
    int*   deg      = (int*)w;    w += N_NODES * 4;
    float* colsum   = (float*)w;  w += 128 * 4;
    float* colsq    = (float*)w;  w += 128 * 4;
    // ---- end of zero region: (N_NODES + 256) ints ----
    int*   eoff     = (int*)w;    w += N_EDGES * 4;
    int*   rowptr   = (int*)w;    w += 50004 * 4;
    float* norm     = (float*)w;  w += N_NODES * 4;
    float* norm2    = (float*)w;  w += N_NODES * 4;
    int*   blocksum = (int*)w;    w += 128 * 4;
    int*   blockoff = (int*)w;    w += 128 * 4;
    int*   csr      = (int*)w;    w += CSR_CAP * 4;
    float* Wt       = (float*)w;  w += IN_DIM * OUT_DIM * 4;
    float* bp       = (float*)w;  w += 64 * 4;
    // align row buffers to 256 B
    w = (char*)(((size_t)w + 255) & ~(size_t)255);
    const size_t HB = (size_t)(N_NODES + 1) * ROW_PAD * 4;   // padded rows + zero row
    uint*  fs       = (uint*)w;   w += HB;
    uint*  bufA     = (uint*)w;   w += HB;
    uint*  bufB     = (uint*)w;   w += HB;

    // 1. zero {deg, colsum, colsq} + zero pad-rows
    {
        int nz = N_NODES + 256;
        zero_kernel<<<(nz + 255) / 256, 256, 0, stream>>>(deg, nz, fs, bufA, bufB);
    }
    // 2. in-degree + per-edge slot (single atomic per edge total)
    deg_kernel<<<(N_EDGES + 255) / 256, 256, 0, stream>>>(dst, deg, eoff);
    // 3. rowptr over 8-aligned degrees + norm/norm2; scan3 also fills CSR pad slots
    scan1_kernel<<<NSCAN_BLK, SCAN_B, 0, stream>>>(deg, rowptr, norm, norm2, blocksum);
    scan2_kernel<<<1, 128, 0, stream>>>(blocksum, blockoff, rowptr);
    scan3_kernel<<<NSCAN_BLK, SCAN_B, 0, stream>>>(rowptr, blockoff, deg, csr);
    // 4. CSR scatter (no atomics)
    csr_fill_kernel<<<(N_EDGES + 255) / 256, 256, 0, stream>>>(src, dst, rowptr, eoff, csr);
    // 5. pre-scale feat by norm into padded bf16 rows
    prescale_kernel<<<(N_NODES * 16 + 255) / 256, 256, 0, stream>>>(feat, norm, (uint4*)fs);
    // 6. three hops: g1 = norm2*S(fs); g2 = norm2*S(g1); h3 = norm*S(g2)
    spmm_kernel<<<N_NODES / 2, 128, 0, stream>>>((const uint4*)fs, rowptr, csr, norm2, (uint4*)bufA);
    spmm_kernel<<<N_NODES / 2, 128, 0, stream>>>((const uint4*)bufA, rowptr, csr, norm2, (uint4*)bufB);
    spmm_kernel<<<N_NODES / 2, 128, 0, stream>>>((const uint4*)bufB, rowptr, csr, norm, (uint4*)bufA);
    // 7. column stats on padded bf16 h3
    col_stats_kernel<<<CS_BLOCKS, CS_THREADS, 0, stream>>>(bufA, colsum, colsq);
    // 8. fold mean/std into W', b'
    prep_kernel<<<1, 256, 0, stream>>>(colsum, colsq, W, b, Wt, bp);
    // 9. final linear (10 threads per node)
    {
        int total = N_NODES * 10;
        final_kernel<<<(total + 255) / 256, 256, 0, stream>>>((const uint4*)bufA, Wt, bp, out);
    }
}